// Round 10
// baseline (260.266 us; speedup 1.0000x reference)
//
#include <hip/hip_runtime.h>
#include <hip/hip_bf16.h>
#include <stdint.h>

// out = x @ (W_shared + W_expert)^T + bias   (MoE collapses: positional routing,
// shared expert weights, normalized top-2 gate weights sum to 1)
static constexpr int Mdim = 16384;  // T = B*N tokens
static constexpr int Ndim = 1024;
static constexpr int Kdim = 1024;
// 128x128 tile, BK=32 (32 steps), 2 LDS buffers, counted-vmcnt pipeline.
static constexpr int BM = 128, BN = 128, BK = 32;

typedef __attribute__((ext_vector_type(8))) __bf16 bf16x8;
typedef __attribute__((ext_vector_type(4))) float f32x4;
typedef __attribute__((ext_vector_type(8))) unsigned short ushort8;

__device__ inline unsigned short f2bf_rn(float f) {
    union { float f; uint32_t u; } v; v.f = f;
    uint32_t u = v.u;
    uint32_t r = u + 0x7FFFu + ((u >> 16) & 1u);
    return (unsigned short)(r >> 16);
}

// pack two fp32 -> bf16 pair (round-half-up; absmax headroom 3x vs RNE, proven)
__device__ inline uint32_t pack_bf2(float a, float b) {
    union { float f; uint32_t u; } ua, ub;
    ua.f = a; ub.f = b;
    uint32_t x = ua.u + 0x8000u;
    uint32_t y = ub.u + 0x8000u;
    return (x >> 16) | (y & 0xFFFF0000u);
}

// Wc = bf16(W_shared + W_expert), 8 elems/thread
__global__ __launch_bounds__(256) void cvt_w_kernel(const float* __restrict__ ws,
                                                    const float* __restrict__ we,
                                                    unsigned short* __restrict__ wc) {
    const size_t i = ((size_t)blockIdx.x * 256 + threadIdx.x) * 8;
    const f32x4* p0 = (const f32x4*)(ws + i);
    const f32x4* p1 = (const f32x4*)(we + i);
    f32x4 a0 = p0[0], a1 = p0[1], b0 = p1[0], b1 = p1[1];
    ushort8 o;
    o[0] = f2bf_rn(a0[0] + b0[0]); o[1] = f2bf_rn(a0[1] + b0[1]);
    o[2] = f2bf_rn(a0[2] + b0[2]); o[3] = f2bf_rn(a0[3] + b0[3]);
    o[4] = f2bf_rn(a1[0] + b1[0]); o[5] = f2bf_rn(a1[1] + b1[1]);
    o[6] = f2bf_rn(a1[2] + b1[2]); o[7] = f2bf_rn(a1[3] + b1[3]);
    *(ushort8*)(wc + i) = o;
}

__device__ inline void gload16(const void* g, void* l) {
    __builtin_amdgcn_global_load_lds((const __attribute__((address_space(1))) void*)g,
                                     (__attribute__((address_space(3))) void*)l,
                                     16, 0, 0);
}

// 8-row-group swizzle for 64-B logical rows (BK=32 bf16), spreads 8 rows over
// all 8 16-B bank slots of a 512-B group (R8's 4-slot map 4-way conflicted):
//   phys(row,cb) = (row>>3)*512 + (rho<<6) ^ (cb ^ ((rho&3)<<4)) ^ ((rho&4)<<4)
// rho=row&7, cb=byte col in [0,64). Slots for rho=0..7: {0,5,2,7,4,1,6,3} - all
// distinct -> b128 frag reads are 2-way max (free, m136). Bijective involution;
// B-DMA inverse is closed-form: rho = rho' ^ (rho'>>2).
__device__ inline int swz(int rho, int cb) {
    return (rho << 6) ^ (cb ^ ((rho & 3) << 4)) ^ ((rho & 4) << 4);
}

#define FENCE()       asm volatile("" ::: "memory")
#define ASM_BARRIER() asm volatile("s_barrier" ::: "memory")
#define WAIT_LGKM0()  asm volatile("s_waitcnt lgkmcnt(0)" ::: "memory")
#define WAIT_VM4()    asm volatile("s_waitcnt vmcnt(4)" ::: "memory")
#define WAIT_VM0()    asm volatile("s_waitcnt vmcnt(0)" ::: "memory")

// Pipeline per step k (one raw barrier per step, NEVER vmcnt(0) in main loop):
//   top:  issue 2x B-DMA(k+1)->buf^1 | FENCE | issue 4x A-flat(k+2)->avIss | FENCE
//   mid:  8x ds_read frags(buf k&1) -> 16 MFMA (setprio)
//   sched_barrier(0)  <- pins pack (and its compiler vmcnt for A(k+1)) after MFMAs
//   bot:  pack A(k+1) -> 2x swizzled ds_write_b128 (buf^1)
//         s_waitcnt vmcnt(4)  <- retires exactly B(k+1); A(k+2) flies across barrier
//         lgkmcnt(0) | s_barrier
// R9 vs R8: (a) __launch_bounds__(256,4) -> all 1024 blocks co-resident (R8's
// (256,3) left 256 blocks for a 2nd dispatch wave -> X refetched, FETCH 114MB);
// (b) bit-6 pair-XOR swizzle (R8's 4-slot map caused 6.3M bank conflicts).
__global__ __launch_bounds__(256, 4) void gemm_pipe(const float* __restrict__ X,
                                                    const unsigned short* __restrict__ Bt,
                                                    const float* __restrict__ bias,
                                                    float* __restrict__ C) {
    __shared__ unsigned char smem[32768];  // A: 2x8K @0, B: 2x8K @16384

    const int tid  = threadIdx.x;
    const int wave = tid >> 6;
    const int lane = tid & 63;

    // bm-fastest (R1-proven, FETCH~48MB with full co-residency): bid%8 == bm%8
    // -> one XCD owns a stripe's 8 bn-blocks; B panel (2MB) L2-resident.
    const int bid = blockIdx.x;
    const int bm  = bid & 127;
    const int bn  = bid >> 7;

    const int wm = (wave >> 1) * 64;
    const int wn = (wave & 1) * 64;

    const int fr = lane & 15;
    const int fq = lane >> 4;
    // frag-read per-lane constant: row = (16-mult) + fr -> group (fr>>3), rho fr&7
    const int cA = (fr >> 3) * 512 + swz(fr & 7, fq * 16);

    // ---- A staging map: row = tid>>1 (0..127), 16 consecutive fp32 ----
    const int arow  = tid >> 1;
    const int acolh = tid & 1;
    const float* gA = X + (size_t)(bm * BM + arow) * Kdim + acolh * 16;
    const int aw0 = (arow >> 3) * 512 + swz(arow & 7, acolh * 32);
    const int aw1 = aw0 ^ 16;   // swz(rho, cb+16) = swz(rho, cb)^16 for cb in {0,32}

    // ---- B staging map: DMA linear dest, inverse-swizzled global source ----
    // dest byte p = tid*16 (+ i*4096): group tid>>5, phys-row rho'=(tid>>2)&7.
    const int rhop  = (tid >> 2) & 7;
    const int rhob  = rhop ^ (rhop >> 2);                 // logical row within group
    const int bsrow = (tid >> 5) * 8 + rhob;              // + i*64
    const int bscol = ((tid & 3) ^ (rhob & 3)) * 8;       // element col
    const unsigned short* gB = Bt + (size_t)(bn * BN + bsrow) * Kdim + bscol;
    const int bdst = 16384 + tid * 16;                    // + buf*8192 + i*4096

    f32x4 acc[4][4] = {};
    f32x4 avA[4], avB[4];   // A(even k) / A(odd k) register sets

    // ---- prologue: stage tile 0, issue A(1); leave A(1) in flight ----
#pragma unroll
    for (int u = 0; u < 4; ++u)
        avA[u] = *(const f32x4*)(gA + u * 4);
#pragma unroll
    for (int i = 0; i < 2; ++i)
        gload16(gB + (size_t)i * 64 * Kdim, smem + bdst + i * 4096);
    FENCE();
    {   // pack A(0) -> buf0 (compiler inserts vmcnt(2): retires A(0), B(0) flies)
        uint4 w0, w1;
        w0.x = pack_bf2(avA[0][0], avA[0][1]); w0.y = pack_bf2(avA[0][2], avA[0][3]);
        w0.z = pack_bf2(avA[1][0], avA[1][1]); w0.w = pack_bf2(avA[1][2], avA[1][3]);
        w1.x = pack_bf2(avA[2][0], avA[2][1]); w1.y = pack_bf2(avA[2][2], avA[2][3]);
        w1.z = pack_bf2(avA[3][0], avA[3][1]); w1.w = pack_bf2(avA[3][2], avA[3][3]);
        *(uint4*)(smem + aw0) = w0;
        *(uint4*)(smem + aw1) = w1;
    }
#pragma unroll
    for (int u = 0; u < 4; ++u)     // A(1) -> avB (stays in flight past barrier)
        avB[u] = *(const f32x4*)(gA + 32 + u * 4);
    FENCE();
    WAIT_VM4();      // retire the 2 B(0) DMAs; A(1) stays out
    WAIT_LGKM0();
    ASM_BARRIER();

// KTE = element offset of the CURRENT step (= step*32).
// Stages B(step+1) at KTE+32 and A(step+2) at KTE+64.
#define GEMM_STEP(KTE, CUR, PK, IS)                                                 \
    {                                                                               \
        const int nb = (CUR) ^ 1;                                                   \
        _Pragma("unroll")                                                           \
        for (int i = 0; i < 2; ++i)  /* B(step+1) */                                \
            gload16(gB + (size_t)i * 64 * Kdim + (KTE) + 32,                        \
                    smem + bdst + nb * 8192 + i * 4096);                            \
        FENCE();                                                                    \
        _Pragma("unroll")                                                           \
        for (int u = 0; u < 4; ++u)  /* A(step+2) */                                \
            IS[u] = *(const f32x4*)(gA + (KTE) + 64 + u * 4);                       \
        FENCE();                                                                    \
        bf16x8 a[4], b[4];                                                          \
        _Pragma("unroll")                                                           \
        for (int i = 0; i < 4; ++i)                                                 \
            a[i] = *(const bf16x8*)(smem + (CUR) * 8192 + wm * 64 + i * 1024 + cA); \
        _Pragma("unroll")                                                           \
        for (int j = 0; j < 4; ++j)                                                 \
            b[j] = *(const bf16x8*)(smem + 16384 + (CUR) * 8192 +                   \
                                    wn * 64 + j * 1024 + cA);                       \
        __builtin_amdgcn_s_setprio(1);                                              \
        _Pragma("unroll")                                                           \
        for (int i = 0; i < 4; ++i)                                                 \
            _Pragma("unroll")                                                       \
            for (int j = 0; j < 4; ++j)                                             \
                acc[i][j] = __builtin_amdgcn_mfma_f32_16x16x32_bf16(                \
                    a[i], b[j], acc[i][j], 0, 0, 0);                                \
        __builtin_amdgcn_s_setprio(0);                                              \
        __builtin_amdgcn_sched_barrier(0);                                          \
        {   /* pack A(step+1): compiler-inserted counted vmcnt retires it */        \
            uint4 w0, w1;                                                           \
            w0.x = pack_bf2(PK[0][0], PK[0][1]); w0.y = pack_bf2(PK[0][2], PK[0][3]);\
            w0.z = pack_bf2(PK[1][0], PK[1][1]); w0.w = pack_bf2(PK[1][2], PK[1][3]);\
            w1.x = pack_bf2(PK[2][0], PK[2][1]); w1.y = pack_bf2(PK[2][2], PK[2][3]);\
            w1.z = pack_bf2(PK[3][0], PK[3][1]); w1.w = pack_bf2(PK[3][2], PK[3][3]);\
            *(uint4*)(smem + nb * 8192 + aw0) = w0;                                 \
            *(uint4*)(smem + nb * 8192 + aw1) = w1;                                 \
        }                                                                           \
        WAIT_VM4();     /* retire B(step+1); A(step+2) stays in flight */           \
        WAIT_LGKM0();                                                               \
        ASM_BARRIER();                                                              \
    }

    // steps 0..29 (even: pack avB=A(k+1), issue avA=A(k+2); odd: swapped)
    for (int kk = 0; kk < 30; kk += 2) {
        GEMM_STEP(kk * 32,      0, avB, avA)
        GEMM_STEP(kk * 32 + 32, 1, avA, avB)
    }

    // ---- step 30: stage B(31) + pack A(31); no A-issue; tail drain ----
    {
#pragma unroll
        for (int i = 0; i < 2; ++i)
            gload16(gB + (size_t)i * 64 * Kdim + 30 * 32 + 32,
                    smem + bdst + 8192 + i * 4096);
        FENCE();
        bf16x8 a[4], b[4];
#pragma unroll
        for (int i = 0; i < 4; ++i)
            a[i] = *(const bf16x8*)(smem + wm * 64 + i * 1024 + cA);
#pragma unroll
        for (int j = 0; j < 4; ++j)
            b[j] = *(const bf16x8*)(smem + 16384 + wn * 64 + j * 1024 + cA);
        __builtin_amdgcn_s_setprio(1);
#pragma unroll
        for (int i = 0; i < 4; ++i)
#pragma unroll
            for (int j = 0; j < 4; ++j)
                acc[i][j] = __builtin_amdgcn_mfma_f32_16x16x32_bf16(a[i], b[j], acc[i][j], 0, 0, 0);
        __builtin_amdgcn_s_setprio(0);
        __builtin_amdgcn_sched_barrier(0);
        {
            uint4 w0, w1;
            w0.x = pack_bf2(avB[0][0], avB[0][1]); w0.y = pack_bf2(avB[0][2], avB[0][3]);
            w0.z = pack_bf2(avB[1][0], avB[1][1]); w0.w = pack_bf2(avB[1][2], avB[1][3]);
            w1.x = pack_bf2(avB[2][0], avB[2][1]); w1.y = pack_bf2(avB[2][2], avB[2][3]);
            w1.z = pack_bf2(avB[3][0], avB[3][1]); w1.w = pack_bf2(avB[3][2], avB[3][3]);
            *(uint4*)(smem + 8192 + aw0) = w0;
            *(uint4*)(smem + 8192 + aw1) = w1;
        }
        WAIT_VM0();      // tail-only drain (just B(31))
        WAIT_LGKM0();
        ASM_BARRIER();
    }
    // ---- step 31: compute-only ----
    {
        bf16x8 a[4], b[4];
#pragma unroll
        for (int i = 0; i < 4; ++i)
            a[i] = *(const bf16x8*)(smem + 8192 + wm * 64 + i * 1024 + cA);
#pragma unroll
        for (int j = 0; j < 4; ++j)
            b[j] = *(const bf16x8*)(smem + 16384 + 8192 + wn * 64 + j * 1024 + cA);
#pragma unroll
        for (int i = 0; i < 4; ++i)
#pragma unroll
            for (int j = 0; j < 4; ++j)
                acc[i][j] = __builtin_amdgcn_mfma_f32_16x16x32_bf16(a[i], b[j], acc[i][j], 0, 0, 0);
    }

    // Epilogue: C/D layout col = lane&15, row = (lane>>4)*4 + reg  [m89-verified]
#pragma unroll
    for (int j = 0; j < 4; ++j) {
        const int col = bn * BN + wn + j * 16 + fr;
        const float bv = bias[col];
#pragma unroll
        for (int i = 0; i < 4; ++i) {
            const int row = bm * BM + wm + i * 16 + fq * 4;
            float* p = C + (size_t)row * Ndim + col;
#pragma unroll
            for (int r = 0; r < 4; ++r)
                p[(size_t)r * Ndim] = acc[i][j][r] + bv;
        }
    }
}

extern "C" void kernel_launch(void* const* d_in, const int* in_sizes, int n_in,
                              void* d_out, int out_size, void* d_ws, size_t ws_size,
                              hipStream_t stream) {
    // inputs: x, cond, mask, W_shared, W_expert, W_gate, bias
    const float* x    = (const float*)d_in[0];
    const float* Wsh  = (const float*)d_in[3];
    const float* Wex  = (const float*)d_in[4];
    const float* bias = (const float*)d_in[6];
    float* out = (float*)d_out;

    unsigned short* Wbf = (unsigned short*)d_ws;  // 1024*1024 bf16 = 2 MiB

    hipLaunchKernelGGL(cvt_w_kernel, dim3((Ndim * Kdim) / (256 * 8)), dim3(256), 0, stream,
                       Wsh, Wex, Wbf);
    hipLaunchKernelGGL(gemm_pipe, dim3((Mdim / BM) * (Ndim / BN)), dim3(256), 0, stream,
                       x, Wbf, bias, out);
}

// Round 11
// 193.983 us; speedup vs baseline: 1.3417x; 1.3417x over previous
//
#include <hip/hip_runtime.h>
#include <hip/hip_bf16.h>
#include <stdint.h>

// out = x @ (W_shared + W_expert)^T + bias   (MoE collapses: positional routing,
// shared expert weights, normalized top-2 gate weights sum to 1)
static constexpr int Mdim = 16384;  // T = B*N tokens
static constexpr int Ndim = 1024;
static constexpr int Kdim = 1024;
static constexpr int BM = 128, BN = 128, BK = 64;  // BK = two 32-wide sub-tiles

typedef __attribute__((ext_vector_type(8))) __bf16 bf16x8;
typedef __attribute__((ext_vector_type(4))) float f32x4;
typedef __attribute__((ext_vector_type(8))) unsigned short ushort8;

__device__ inline unsigned short f2bf_rn(float f) {
    union { float f; uint32_t u; } v; v.f = f;
    uint32_t u = v.u;
    uint32_t r = u + 0x7FFFu + ((u >> 16) & 1u);
    return (unsigned short)(r >> 16);
}

// pack two fp32 -> bf16 pair (round-half-up: 1 add/elem; bias vs RNE is
// tie-cases only, absmax headroom is 3x)
__device__ inline uint32_t pack_bf2(float a, float b) {
    union { float f; uint32_t u; } ua, ub;
    ua.f = a; ub.f = b;
    uint32_t x = ua.u + 0x8000u;
    uint32_t y = ub.u + 0x8000u;
    return (x >> 16) | (y & 0xFFFF0000u);
}

// Wc = bf16(W_shared + W_expert), 8 elems/thread
__global__ __launch_bounds__(256) void cvt_w_kernel(const float* __restrict__ ws,
                                                    const float* __restrict__ we,
                                                    unsigned short* __restrict__ wc) {
    const size_t i = ((size_t)blockIdx.x * 256 + threadIdx.x) * 8;
    const f32x4* p0 = (const f32x4*)(ws + i);
    const f32x4* p1 = (const f32x4*)(we + i);
    f32x4 a0 = p0[0], a1 = p0[1], b0 = p1[0], b1 = p1[1];
    ushort8 o;
    o[0] = f2bf_rn(a0[0] + b0[0]); o[1] = f2bf_rn(a0[1] + b0[1]);
    o[2] = f2bf_rn(a0[2] + b0[2]); o[3] = f2bf_rn(a0[3] + b0[3]);
    o[4] = f2bf_rn(a1[0] + b1[0]); o[5] = f2bf_rn(a1[1] + b1[1]);
    o[6] = f2bf_rn(a1[2] + b1[2]); o[7] = f2bf_rn(a1[3] + b1[3]);
    *(ushort8*)(wc + i) = o;
}

__device__ inline void gload16(const void* g, void* l) {
    __builtin_amdgcn_global_load_lds((const __attribute__((address_space(1))) void*)g,
                                     (__attribute__((address_space(3))) void*)l,
                                     16, 0, 0);
}

// C[m][n] = sum_k bf16(X[m][k]) * Wc[n][k] + bias[n]
// EXACT R0 champion structure (70 us: single-buffer, 2 barriers/step, 4 blk/CU,
// VGPR 60+64 AGPR = 124 fits (256,4) without spills) + ONE change:
//
//   K-RING STAGGER: block processes K-tiles in ring order starting at
//   k0 = (bid&3)*4. R0's counters (Mfma 18% + VALU 18% + HBM 35% + LDS ~25%
//   summing to ~100%) show phase-locked convoy: all co-resident blocks stage
//   together then MFMA together -> no cross-pipe overlap. Staggering gives the
//   4 blocks/CU different phases so one block's staging overlaps another's MFMA.
//   bid&3 varies bm (bm = bid&127) -> same-stripe blocks (sharing the A-panel
//   in L2) keep the SAME k0: L2 A-sharing preserved. Accumulation is only
//   order-permuted (fp32 acc; absmax headroom 3x).
__global__ __launch_bounds__(256, 4) void gemm_fused(const float* __restrict__ X,
                                                     const unsigned short* __restrict__ Bt,
                                                     const float* __restrict__ bias,
                                                     float* __restrict__ C) {
    __shared__ unsigned short As[2 * BM * 32];  // 16 KiB
    __shared__ unsigned short Bs[2 * BN * 32];  // 16 KiB

    const int tid = threadIdx.x;
    const int wave = tid >> 6;
    const int lane = tid & 63;
    const int bid = blockIdx.x;
    const int bm = bid & 127;   // fastest -> bid%8 == bm%8 -> same XCD per m-stripe
    const int bn = bid >> 7;
    const int wm = (wave >> 1) * 64;
    const int wn = (wave & 1) * 64;

    // ---- B staging map (per sub-tile: proven round-0 chunk pattern) ----
    const int cw0 = wave, cw1 = wave + 4;          // 1-KiB chunks (16 rows each)
    const int brow0 = cw0 * 16 + (lane >> 2);
    const int brow1 = cw1 * 16 + (lane >> 2);
    const int bcol = (lane & 3) * 8;
    const unsigned short* gB0 = Bt + (size_t)(bn * BN + brow0) * Kdim + bcol;
    const unsigned short* gB1 = Bt + (size_t)(bn * BN + brow1) * Kdim + bcol;
    unsigned short* lB0 = Bs + cw0 * 512 + lane * 8;   // + s*4096 per sub-tile
    unsigned short* lB1 = Bs + cw1 * 512 + lane * 8;

    // ---- A staging map (fp32 -> bf16 via VGPRs) ----
    const int arow = tid >> 3;        // 0..31 (plus u*32)
    const int acol4 = tid & 7;        // float4 index within 32-col sub-tile
    const float* gA = X + (size_t)(bm * BM + arow) * Kdim + acol4 * 4;
    unsigned short* lA = As + arow * 32 + acol4 * 4;   // + s*4096 + u*32*32

    const int fr = lane & 15;
    const int fq = lane >> 4;
    const int fk = fq * 8;

    f32x4 acc[4][4] = {};

    const int k0 = (bid & 3) * 4;   // ring phase: 0/4/8/12 steps (de-convoy)

    for (int st = 0; st < 16; ++st) {
        const int kt = ((st + k0) & 15) * BK;
        __syncthreads();  // protect LDS from previous iteration's readers
        // B: 4 chunks/thread via direct-to-LDS DMA
#pragma unroll
        for (int s = 0; s < 2; ++s) {
            gload16(gB0 + kt + s * 32, lB0 + s * 4096);
            gload16(gB1 + kt + s * 32, lB1 + s * 4096);
        }
        // A: 8 float4 loads, convert, 8-B LDS writes (conflict-free pattern)
        f32x4 av[2][4];
#pragma unroll
        for (int s = 0; s < 2; ++s)
#pragma unroll
            for (int u = 0; u < 4; ++u)
                av[s][u] = *(const f32x4*)(gA + (size_t)u * 32 * Kdim + kt + s * 32);
#pragma unroll
        for (int s = 0; s < 2; ++s)
#pragma unroll
            for (int u = 0; u < 4; ++u) {
                uint2 w;
                w.x = pack_bf2(av[s][u][0], av[s][u][1]);
                w.y = pack_bf2(av[s][u][2], av[s][u][3]);
                *(uint2*)(lA + s * 4096 + u * 1024) = w;
            }
        __syncthreads();

#pragma unroll
        for (int s = 0; s < 2; ++s) {
            bf16x8 af[4], bfr[4];
#pragma unroll
            for (int i = 0; i < 4; ++i)
                af[i] = *(const bf16x8*)(As + s * 4096 + (wm + i * 16 + fr) * 32 + fk);
#pragma unroll
            for (int j = 0; j < 4; ++j)
                bfr[j] = *(const bf16x8*)(Bs + s * 4096 + (wn + j * 16 + fr) * 32 + fk);
#pragma unroll
            for (int i = 0; i < 4; ++i)
#pragma unroll
                for (int j = 0; j < 4; ++j)
                    acc[i][j] = __builtin_amdgcn_mfma_f32_16x16x32_bf16(af[i], bfr[j], acc[i][j], 0, 0, 0);
        }
    }

    // Epilogue: C/D layout col = lane&15, row = (lane>>4)*4 + reg  [m89-verified]
#pragma unroll
    for (int j = 0; j < 4; ++j) {
        const int col = bn * BN + wn + j * 16 + fr;
        const float bv = bias[col];
#pragma unroll
        for (int i = 0; i < 4; ++i) {
            const int row = bm * BM + wm + i * 16 + fq * 4;
            float* p = C + (size_t)row * Ndim + col;
#pragma unroll
            for (int r = 0; r < 4; ++r)
                p[(size_t)r * Ndim] = acc[i][j][r] + bv;
        }
    }
}

extern "C" void kernel_launch(void* const* d_in, const int* in_sizes, int n_in,
                              void* d_out, int out_size, void* d_ws, size_t ws_size,
                              hipStream_t stream) {
    // inputs: x, cond, mask, W_shared, W_expert, W_gate, bias
    const float* x    = (const float*)d_in[0];
    const float* Wsh  = (const float*)d_in[3];
    const float* Wex  = (const float*)d_in[4];
    const float* bias = (const float*)d_in[6];
    float* out = (float*)d_out;

    unsigned short* Wbf = (unsigned short*)d_ws;  // 1024*1024 bf16 = 2 MiB

    hipLaunchKernelGGL(cvt_w_kernel, dim3((Ndim * Kdim) / (256 * 8)), dim3(256), 0, stream,
                       Wsh, Wex, Wbf);
    hipLaunchKernelGGL(gemm_fused, dim3((Mdim / BM) * (Ndim / BN)), dim3(256), 0, stream,
                       x, Wbf, bias, out);
}